// Round 1
// baseline (950.286 us; speedup 1.0000x reference)
//
#include <hip/hip_runtime.h>
#include <hip/hip_fp16.h>

// Problem constants
#define BT_N   32768   // B*T queries
#define DDIM   512
#define KCB    4096
#define W_FLAG 0.25f   // gap window: below this, exact fp64 rescore (~10 sigma of fp16 score noise)

typedef _Float16 half8 __attribute__((ext_vector_type(8)));
typedef float    fx4   __attribute__((ext_vector_type(4)));

// ---------------- workspace layout ----------------
static constexpr size_t OFF_XH   = 0;                          // fp16 inputs      32 MB
static constexpr size_t OFF_CH   = OFF_XH   + (size_t)BT_N*DDIM*2;   // fp16 (-2*codebook) 4 MB
static constexpr size_t OFF_CNP  = OFF_CH   + (size_t)KCB*DDIM*2;    // float  cnorm+1024  16 KB
static constexpr size_t OFF_CND  = OFF_CNP  + (size_t)KCB*4;         // double cnorm       32 KB
static constexpr size_t OFF_V0   = OFF_CND  + (size_t)KCB*8;         // per (split,q) top1 val
static constexpr size_t OFF_I0   = OFF_V0   + (size_t)4*BT_N*4;      // per (split,q) top1 idx
static constexpr size_t OFF_V1   = OFF_I0   + (size_t)4*BT_N*4;      // per (split,q) 2nd val
static constexpr size_t OFF_OIDX = OFF_V1   + (size_t)4*BT_N*4;      // final idx / -1 flag
static constexpr size_t OFF_RES  = OFF_OIDX + (size_t)BT_N*4;        // packed fp64 rescore slots
static constexpr size_t OFF_LIST = OFF_RES  + (size_t)BT_N*8;        // flagged query list
static constexpr size_t OFF_CNT  = OFF_LIST + (size_t)BT_N*4;        // flagged counter (4 B)

// ---------------- async 16B global->LDS ----------------
__device__ __forceinline__ void async16(const void* g, void* l) {
    __builtin_amdgcn_global_load_lds(
        (const __attribute__((address_space(1))) unsigned int*)g,
        (__attribute__((address_space(3))) unsigned int*)l,
        16, 0, 0);
}

// ---------------- K_x: convert inputs fp32 -> fp16 ----------------
__global__ __launch_bounds__(256) void vq_cvt_x(const float* __restrict__ X,
                                                _Float16* __restrict__ Xh, int n8) {
    int i = blockIdx.x * 256 + threadIdx.x;
    int stride = gridDim.x * 256;
    for (; i < n8; i += stride) {
        float4 a = ((const float4*)X)[(size_t)i*2];
        float4 b = ((const float4*)X)[(size_t)i*2 + 1];
        half8 h;
        h[0]=(_Float16)a.x; h[1]=(_Float16)a.y; h[2]=(_Float16)a.z; h[3]=(_Float16)a.w;
        h[4]=(_Float16)b.x; h[5]=(_Float16)b.y; h[6]=(_Float16)b.z; h[7]=(_Float16)b.w;
        ((half8*)Xh)[i] = h;
    }
}

// ---------------- K_cb: codebook -> fp16(-2c), cnorm (fp64 + float(+1024)) ----------------
__global__ __launch_bounds__(64) void vq_cvt_cb(const float* __restrict__ CB,
                                                _Float16* __restrict__ Ch,
                                                float* __restrict__ cnormP,
                                                double* __restrict__ cnorm_dp) {
    int r = blockIdx.x;            // code row
    int t = threadIdx.x;           // 64 threads, 8 elems each
    const float* row = CB + (size_t)r * DDIM;
    float4 a = ((const float4*)row)[t*2];
    float4 b = ((const float4*)row)[t*2 + 1];
    double s = (double)a.x*a.x + (double)a.y*a.y + (double)a.z*a.z + (double)a.w*a.w
             + (double)b.x*b.x + (double)b.y*b.y + (double)b.z*b.z + (double)b.w*b.w;
    half8 h;
    h[0]=(_Float16)(-2.0f*a.x); h[1]=(_Float16)(-2.0f*a.y);
    h[2]=(_Float16)(-2.0f*a.z); h[3]=(_Float16)(-2.0f*a.w);
    h[4]=(_Float16)(-2.0f*b.x); h[5]=(_Float16)(-2.0f*b.y);
    h[6]=(_Float16)(-2.0f*b.z); h[7]=(_Float16)(-2.0f*b.w);
    ((half8*)(Ch + (size_t)r * DDIM))[t] = h;
    #pragma unroll
    for (int off = 1; off < 64; off <<= 1) s += __shfl_xor(s, off);
    if (t == 0) { cnorm_dp[r] = s; cnormP[r] = (float)(s + 1024.0); }
}

// ---------------- Kernel A: fp16 MFMA GEMM + fused top-2 tracking ----------------
// grid: 1024 blocks = 256 query-tiles(128) x 4 code-splits(1024). 256 threads = 4 waves (2x2).
#define BM 128
#define BN 128
#define BK 64
__global__ __launch_bounds__(256, 2) void vq_gemm(
    const _Float16* __restrict__ Xh, const _Float16* __restrict__ Ch,
    const float* __restrict__ cnormP,
    float* __restrict__ ws_v0, int* __restrict__ ws_i0, float* __restrict__ ws_v1)
{
    __shared__ _Float16 As[BM * BK];   // 16 KB, rows of 64 halves (8 x 16B slots)
    __shared__ _Float16 Bs[BN * BK];   // 16 KB
    __shared__ float lds_v0[BM][2];
    __shared__ int   lds_i0[BM][2];
    __shared__ float lds_v1[BM][2];

    const int tid   = threadIdx.x;
    const int lane  = tid & 63;
    const int w     = tid >> 6;
    const int wm    = w >> 1, wn = w & 1;
    const int qblk  = blockIdx.x >> 2;
    const int split = blockIdx.x & 3;
    const int m0    = qblk * BM;
    const int nbase = split * 1024;
    const int c16   = lane & 15;
    const int q4    = lane >> 4;

    // per-lane running top-1 (val+idx) and 2nd-best (val only), per owned row (mi,j)
    float v0r[4][4], v1r[4][4]; int i0r[4][4];
    #pragma unroll
    for (int a = 0; a < 4; a++)
        #pragma unroll
        for (int b = 0; b < 4; b++) { v0r[a][b] = 3e38f; v1r[a][b] = 3e38f; i0r[a][b] = 0; }

    // staging pattern: 1024 16B-slots, li = g*256+tid; XOR swizzle on global side
    int srow[4], scol[4], sdst[4];
    #pragma unroll
    for (int g = 0; g < 4; ++g) {
        int li = g * 256 + tid;
        int row = li >> 3, slot = li & 7;
        srow[g] = row;
        scol[g] = ((slot ^ (row & 7)) << 3);   // halves
        sdst[g] = li << 4;                     // bytes
    }

    for (int nt = 0; nt < 8; ++nt) {           // 8 N-tiles of 128 codes
        const int nb = nbase + nt * BN;
        fx4 acc[4][4];
        #pragma unroll
        for (int ni = 0; ni < 4; ++ni) {
            float cn = cnormP[nb + wn * 64 + ni * 16 + c16];
            #pragma unroll
            for (int mi = 0; mi < 4; ++mi) acc[mi][ni] = (fx4){cn, cn, cn, cn};
        }
        for (int kb = 0; kb < DDIM; kb += BK) {
            #pragma unroll
            for (int g = 0; g < 4; ++g)
                async16(Xh + (size_t)(m0 + srow[g]) * DDIM + kb + scol[g], (char*)As + sdst[g]);
            #pragma unroll
            for (int g = 0; g < 4; ++g)
                async16(Ch + (size_t)(nb + srow[g]) * DDIM + kb + scol[g], (char*)Bs + sdst[g]);
            __syncthreads();
            #pragma unroll
            for (int kk = 0; kk < 2; ++kk) {
                half8 af[4], bf[4];
                #pragma unroll
                for (int mi = 0; mi < 4; ++mi) {
                    int r = wm * 64 + mi * 16 + c16;
                    int s = (kk * 4 + q4) ^ (r & 7);
                    af[mi] = *(const half8*)((const char*)As + r * 128 + s * 16);
                }
                #pragma unroll
                for (int ni = 0; ni < 4; ++ni) {
                    int r = wn * 64 + ni * 16 + c16;
                    int s = (kk * 4 + q4) ^ (r & 7);
                    bf[ni] = *(const half8*)((const char*)Bs + r * 128 + s * 16);
                }
                #pragma unroll
                for (int mi = 0; mi < 4; ++mi)
                    #pragma unroll
                    for (int ni = 0; ni < 4; ++ni)
                        acc[mi][ni] = __builtin_amdgcn_mfma_f32_16x16x32_f16(af[mi], bf[ni], acc[mi][ni], 0, 0, 0);
            }
            __syncthreads();
        }
        // epilogue: acc already holds d2p = cnorm+1024-2*x.c. Update per-lane top-2.
        #pragma unroll
        for (int ni = 0; ni < 4; ++ni) {
            int col = nb + wn * 64 + ni * 16 + c16;
            #pragma unroll
            for (int mi = 0; mi < 4; ++mi) {
                #pragma unroll
                for (int j = 0; j < 4; ++j) {
                    float v = acc[mi][ni][j];
                    float old0 = v0r[mi][j];
                    v1r[mi][j] = __builtin_amdgcn_fmed3f(v, old0, v1r[mi][j]);
                    bool lt = v < old0;            // strict: earlier (smaller) col wins ties
                    v0r[mi][j] = lt ? v : old0;
                    i0r[mi][j] = lt ? col : i0r[mi][j];
                }
            }
        }
    }

    // butterfly merge across the 16 lanes of each quad-group
    #pragma unroll
    for (int off = 1; off < 16; off <<= 1) {
        #pragma unroll
        for (int mi = 0; mi < 4; ++mi)
            #pragma unroll
            for (int j = 0; j < 4; ++j) {
                float ov0 = __shfl_xor(v0r[mi][j], off);
                int   oi0 = __shfl_xor(i0r[mi][j], off);
                float ov1 = __shfl_xor(v1r[mi][j], off);
                float nv1 = fminf(fmaxf(v0r[mi][j], ov0), fminf(v1r[mi][j], ov1));
                bool take = (ov0 < v0r[mi][j]) || (ov0 == v0r[mi][j] && oi0 < i0r[mi][j]);
                v0r[mi][j] = take ? ov0 : v0r[mi][j];
                i0r[mi][j] = take ? oi0 : i0r[mi][j];
                v1r[mi][j] = nv1;
            }
    }
    if (c16 == 0) {
        #pragma unroll
        for (int mi = 0; mi < 4; ++mi)
            #pragma unroll
            for (int j = 0; j < 4; ++j) {
                int r = wm * 64 + mi * 16 + q4 * 4 + j;
                lds_v0[r][wn] = v0r[mi][j];
                lds_i0[r][wn] = i0r[mi][j];
                lds_v1[r][wn] = v1r[mi][j];
            }
    }
    __syncthreads();
    if (tid < BM) {
        float a0 = lds_v0[tid][0], b0 = lds_v0[tid][1];
        int   ai = lds_i0[tid][0], bi = lds_i0[tid][1];
        float a1 = lds_v1[tid][0], b1 = lds_v1[tid][1];
        float v1 = fminf(fmaxf(a0, b0), fminf(a1, b1));
        bool take = (b0 < a0) || (b0 == a0 && bi < ai);
        float v0 = take ? b0 : a0;
        int   i0 = take ? bi : ai;
        size_t o = (size_t)split * BT_N + m0 + tid;
        ws_v0[o] = v0; ws_i0[o] = i0; ws_v1[o] = v1;
    }
}

// ---------------- Kernel M: merge splits, flag close calls ----------------
__global__ __launch_bounds__(256) void vq_merge(
    const float* __restrict__ ws_v0, const int* __restrict__ ws_i0, const float* __restrict__ ws_v1,
    int* __restrict__ out_idx, unsigned long long* __restrict__ res,
    int* __restrict__ list, unsigned int* __restrict__ counter)
{
    int q = blockIdx.x * 256 + threadIdx.x;
    float v0 = ws_v0[q]; int i0 = ws_i0[q]; float v1 = ws_v1[q];
    #pragma unroll
    for (int s = 1; s < 4; ++s) {
        size_t o = (size_t)s * BT_N + q;
        float sv0 = ws_v0[o]; int si0 = ws_i0[o]; float sv1 = ws_v1[o];
        v1 = fminf(fmaxf(v0, sv0), fminf(v1, sv1));
        bool take = (sv0 < v0) || (sv0 == v0 && si0 < i0);
        if (take) { v0 = sv0; i0 = si0; }
    }
    res[q] = 0x7FF0000000000000ull;   // +inf pattern for rescore atomicMin
    if (v1 - v0 < W_FLAG) {
        out_idx[q] = -1;
        unsigned int pos = atomicAdd(counter, 1u);
        list[pos] = q;
    } else {
        out_idx[q] = i0;
    }
}

// ---------------- Kernel R: exact fp64 rescore of flagged queries over ALL codes ----------------
// grid (256 code-chunks of 16, 8 query stripes) x 256 threads
__global__ __launch_bounds__(256) void vq_rescore(
    const float* __restrict__ X, const float* __restrict__ CB,
    const double* __restrict__ cnorm_dp,
    const int* __restrict__ list, const unsigned int* __restrict__ counter,
    unsigned long long* __restrict__ res)
{
    __shared__ float cbs[16 * DDIM];   // 32 KB: this block's 16 codebook rows
    __shared__ float xs[DDIM];
    const int tid = threadIdx.x;
    const int c0 = blockIdx.x * 16;
    const unsigned int stripe = blockIdx.y;      // 0..7
    for (int i = tid; i < 16 * DDIM / 4; i += 256)
        ((float4*)cbs)[i] = ((const float4*)(CB + (size_t)c0 * DDIM))[i];
    const unsigned int cnt = *counter;
    const int code = c0 + (tid >> 4);
    const int dpart = tid & 15;
    const double cn = cnorm_dp[code];
    __syncthreads();
    for (unsigned int i = stripe; i < cnt; i += 8) {
        int q = list[i];
        __syncthreads();                          // protect xs reuse
        if (tid < 128) ((float4*)xs)[tid] = ((const float4*)(X + (size_t)q * DDIM))[tid];
        __syncthreads();
        const float* xp = xs + dpart * 32;
        const float* cp = cbs + (tid >> 4) * DDIM + dpart * 32;
        double dot = 0.0;
        #pragma unroll
        for (int d = 0; d < 32; ++d) dot = fma((double)xp[d], (double)cp[d], dot);
        #pragma unroll
        for (int off = 1; off < 16; off <<= 1) dot += __shfl_xor(dot, off);
        if (dpart == 0) {
            double d2 = cn - 2.0 * dot + 4096.0;  // positive -> bit-order == numeric order
            unsigned long long p =
                (__double_as_longlong(d2) & ~0xFFFull) | (unsigned long long)code;
            atomicMin(res + q, p);
        }
    }
}

// ---------------- Kernel G: gather codebook rows ----------------
__global__ __launch_bounds__(128) void vq_gather(
    const float* __restrict__ CB, const int* __restrict__ out_idx,
    const unsigned long long* __restrict__ res, float* __restrict__ out)
{
    int q = blockIdx.x;
    int idx = out_idx[q];
    if (idx < 0) idx = (int)(res[q] & 0xFFFull);
    int t = threadIdx.x;
    ((float4*)(out + (size_t)q * DDIM))[t] = ((const float4*)(CB + (size_t)idx * DDIM))[t];
}

// ---------------- launcher ----------------
extern "C" void kernel_launch(void* const* d_in, const int* in_sizes, int n_in,
                              void* d_out, int out_size, void* d_ws, size_t ws_size,
                              hipStream_t stream) {
    const float* X  = (const float*)d_in[0];   // [32768,512]
    const float* CB = (const float*)d_in[1];   // [4096,512]
    float* out = (float*)d_out;

    char* ws = (char*)d_ws;
    _Float16* Xh       = (_Float16*)(ws + OFF_XH);
    _Float16* Ch       = (_Float16*)(ws + OFF_CH);
    float*    cnormP   = (float*)(ws + OFF_CNP);
    double*   cnorm_dp = (double*)(ws + OFF_CND);
    float*    ws_v0    = (float*)(ws + OFF_V0);
    int*      ws_i0    = (int*)(ws + OFF_I0);
    float*    ws_v1    = (float*)(ws + OFF_V1);
    int*      out_idx  = (int*)(ws + OFF_OIDX);
    unsigned long long* res = (unsigned long long*)(ws + OFF_RES);
    int*      list     = (int*)(ws + OFF_LIST);
    unsigned int* counter = (unsigned int*)(ws + OFF_CNT);

    hipMemsetAsync(counter, 0, 4, stream);
    vq_cvt_x<<<2048, 256, 0, stream>>>(X, Xh, BT_N * DDIM / 8);
    vq_cvt_cb<<<KCB, 64, 0, stream>>>(CB, Ch, cnormP, cnorm_dp);
    vq_gemm<<<1024, 256, 0, stream>>>(Xh, Ch, cnormP, ws_v0, ws_i0, ws_v1);
    vq_merge<<<BT_N / 256, 256, 0, stream>>>(ws_v0, ws_i0, ws_v1, out_idx, res, list, counter);
    vq_rescore<<<dim3(256, 8), 256, 0, stream>>>(X, CB, cnorm_dp, list, counter, res);
    vq_gather<<<BT_N, 128, 0, stream>>>(CB, out_idx, res, out);
}

// Round 2
// 489.244 us; speedup vs baseline: 1.9424x; 1.9424x over previous
//
#include <hip/hip_runtime.h>
#include <hip/hip_fp16.h>

// Problem constants
#define BT_N   32768   // B*T queries
#define DDIM   512
#define KCB    4096
#define W_FLAG 0.25f   // fp16-pass gap window (~8 sigma of fp16 score noise)
#define W2     0.01f   // refined-pass gap window (25x worst-case refined error)
#define CAP    8192    // max flagged queries handled (expected ~700)
#define NSPLIT 8       // rescan code splits (512 codes each)

typedef _Float16 half8 __attribute__((ext_vector_type(8)));
typedef float    fx4   __attribute__((ext_vector_type(4)));

// ---------------- workspace layout ----------------
static constexpr size_t OFF_XH   = 0;                                // fp16 inputs          32 MB
static constexpr size_t OFF_CH   = OFF_XH   + (size_t)BT_N*DDIM*2;   // fp16 hi(-2c)          4 MB
static constexpr size_t OFF_CL   = OFF_CH   + (size_t)KCB*DDIM*2;    // fp16 lo(-2c)          4 MB
static constexpr size_t OFF_CNP  = OFF_CL   + (size_t)KCB*DDIM*2;    // float  cnorm+1024    16 KB
static constexpr size_t OFF_CND  = OFF_CNP  + (size_t)KCB*4;         // double cnorm         32 KB
static constexpr size_t OFF_V0   = OFF_CND  + (size_t)KCB*8;         // per (split,q) top1 val
static constexpr size_t OFF_I0   = OFF_V0   + (size_t)4*BT_N*4;      // per (split,q) top1 idx
static constexpr size_t OFF_V1   = OFF_I0   + (size_t)4*BT_N*4;      // per (split,q) 2nd val
static constexpr size_t OFF_OIDX = OFF_V1   + (size_t)4*BT_N*4;      // final idx
static constexpr size_t OFF_LIST = OFF_OIDX + (size_t)BT_N*4;        // flagged query list
static constexpr size_t OFF_CNT  = OFF_LIST + (size_t)CAP*4;         // flagged counter
static constexpr size_t OFF_RSV0 = OFF_CNT  + 64;                    // rescan per-split top2
static constexpr size_t OFF_RSI0 = OFF_RSV0 + (size_t)NSPLIT*CAP*4;
static constexpr size_t OFF_RSV1 = OFF_RSI0 + (size_t)NSPLIT*CAP*4;
static constexpr size_t OFF_RSI1 = OFF_RSV1 + (size_t)NSPLIT*CAP*4;

// ---------------- async 16B global->LDS ----------------
__device__ __forceinline__ void async16(const void* g, void* l) {
    __builtin_amdgcn_global_load_lds(
        (const __attribute__((address_space(1))) unsigned int*)g,
        (__attribute__((address_space(3))) unsigned int*)l,
        16, 0, 0);
}

// ---------------- top-2 helpers (smaller-index tie-break, np.argmin semantics) ---
__device__ __forceinline__ void t2_update(float& v0, int& i0, float& v1, int& i1,
                                          float v, int idx) {
    bool t0 = (v < v0) || (v == v0 && idx < i0);
    bool t1 = (v < v1) || (v == v1 && idx < i1);
    float nv1 = t0 ? v0 : (t1 ? v : v1);
    int   ni1 = t0 ? i0 : (t1 ? idx : i1);
    v1 = nv1; i1 = ni1;
    v0 = t0 ? v : v0;
    i0 = t0 ? idx : i0;
}
__device__ __forceinline__ void t2_merge(float& v0, int& i0, float& v1, int& i1,
                                         float ov0, int oi0, float ov1, int oi1) {
    bool oa = (ov0 < v0) || (ov0 == v0 && oi0 < i0);
    float w0 = oa ? ov0 : v0;  int wi0 = oa ? oi0 : i0;
    float l0 = oa ? v0 : ov0;  int li0 = oa ? i0 : oi0;
    float ws = oa ? ov1 : v1;  int wsi = oa ? oi1 : i1;
    bool sb = (l0 < ws) || (l0 == ws && li0 < wsi);
    v0 = w0; i0 = wi0;
    v1 = sb ? l0 : ws; i1 = sb ? li0 : wsi;
}

// ---------------- K_x: convert inputs fp32 -> fp16 ----------------
__global__ __launch_bounds__(256) void vq_cvt_x(const float* __restrict__ X,
                                                _Float16* __restrict__ Xh, int n8) {
    int i = blockIdx.x * 256 + threadIdx.x;
    int stride = gridDim.x * 256;
    for (; i < n8; i += stride) {
        float4 a = ((const float4*)X)[(size_t)i*2];
        float4 b = ((const float4*)X)[(size_t)i*2 + 1];
        half8 h;
        h[0]=(_Float16)a.x; h[1]=(_Float16)a.y; h[2]=(_Float16)a.z; h[3]=(_Float16)a.w;
        h[4]=(_Float16)b.x; h[5]=(_Float16)b.y; h[6]=(_Float16)b.z; h[7]=(_Float16)b.w;
        ((half8*)Xh)[i] = h;
    }
}

// ---------------- K_cb: codebook -> fp16 hi/lo of (-2c), cnorms ----------------
__global__ __launch_bounds__(64) void vq_cvt_cb(const float* __restrict__ CB,
                                                _Float16* __restrict__ Ch,
                                                _Float16* __restrict__ Cl,
                                                float* __restrict__ cnormP,
                                                double* __restrict__ cnorm_dp) {
    int r = blockIdx.x;
    int t = threadIdx.x;
    const float* row = CB + (size_t)r * DDIM;
    float4 a = ((const float4*)row)[t*2];
    float4 b = ((const float4*)row)[t*2 + 1];
    double s = (double)a.x*a.x + (double)a.y*a.y + (double)a.z*a.z + (double)a.w*a.w
             + (double)b.x*b.x + (double)b.y*b.y + (double)b.z*b.z + (double)b.w*b.w;
    float f[8] = {-2.0f*a.x, -2.0f*a.y, -2.0f*a.z, -2.0f*a.w,
                  -2.0f*b.x, -2.0f*b.y, -2.0f*b.z, -2.0f*b.w};
    half8 h, l;
    #pragma unroll
    for (int i = 0; i < 8; ++i) {
        _Float16 hh = (_Float16)f[i];
        h[i] = hh;
        l[i] = (_Float16)(f[i] - (float)hh);
    }
    ((half8*)(Ch + (size_t)r * DDIM))[t] = h;
    ((half8*)(Cl + (size_t)r * DDIM))[t] = l;
    #pragma unroll
    for (int off = 1; off < 64; off <<= 1) s += __shfl_xor(s, off);
    if (t == 0) { cnorm_dp[r] = s; cnormP[r] = (float)(s + 1024.0); }
}

// ---------------- Kernel A: fp16 MFMA GEMM + fused top-2 tracking ----------------
#define BM 128
#define BN 128
#define BK 64
__global__ __launch_bounds__(256, 2) void vq_gemm(
    const _Float16* __restrict__ Xh, const _Float16* __restrict__ Ch,
    const float* __restrict__ cnormP,
    float* __restrict__ ws_v0, int* __restrict__ ws_i0, float* __restrict__ ws_v1)
{
    __shared__ _Float16 As[BM * BK];
    __shared__ _Float16 Bs[BN * BK];
    __shared__ float lds_v0[BM][2];
    __shared__ int   lds_i0[BM][2];
    __shared__ float lds_v1[BM][2];

    const int tid   = threadIdx.x;
    const int lane  = tid & 63;
    const int w     = tid >> 6;
    const int wm    = w >> 1, wn = w & 1;
    const int qblk  = blockIdx.x >> 2;
    const int split = blockIdx.x & 3;
    const int m0    = qblk * BM;
    const int nbase = split * 1024;
    const int c16   = lane & 15;
    const int q4    = lane >> 4;

    float v0r[4][4], v1r[4][4]; int i0r[4][4];
    #pragma unroll
    for (int a = 0; a < 4; a++)
        #pragma unroll
        for (int b = 0; b < 4; b++) { v0r[a][b] = 3e38f; v1r[a][b] = 3e38f; i0r[a][b] = 0; }

    int srow[4], scol[4], sdst[4];
    #pragma unroll
    for (int g = 0; g < 4; ++g) {
        int li = g * 256 + tid;
        int row = li >> 3, slot = li & 7;
        srow[g] = row;
        scol[g] = ((slot ^ (row & 7)) << 3);
        sdst[g] = li << 4;
    }

    for (int nt = 0; nt < 8; ++nt) {
        const int nb = nbase + nt * BN;
        fx4 acc[4][4];
        #pragma unroll
        for (int ni = 0; ni < 4; ++ni) {
            float cn = cnormP[nb + wn * 64 + ni * 16 + c16];
            #pragma unroll
            for (int mi = 0; mi < 4; ++mi) acc[mi][ni] = (fx4){cn, cn, cn, cn};
        }
        for (int kb = 0; kb < DDIM; kb += BK) {
            #pragma unroll
            for (int g = 0; g < 4; ++g)
                async16(Xh + (size_t)(m0 + srow[g]) * DDIM + kb + scol[g], (char*)As + sdst[g]);
            #pragma unroll
            for (int g = 0; g < 4; ++g)
                async16(Ch + (size_t)(nb + srow[g]) * DDIM + kb + scol[g], (char*)Bs + sdst[g]);
            __syncthreads();
            #pragma unroll
            for (int kk = 0; kk < 2; ++kk) {
                half8 af[4], bf[4];
                #pragma unroll
                for (int mi = 0; mi < 4; ++mi) {
                    int r = wm * 64 + mi * 16 + c16;
                    int s = (kk * 4 + q4) ^ (r & 7);
                    af[mi] = *(const half8*)((const char*)As + r * 128 + s * 16);
                }
                #pragma unroll
                for (int ni = 0; ni < 4; ++ni) {
                    int r = wn * 64 + ni * 16 + c16;
                    int s = (kk * 4 + q4) ^ (r & 7);
                    bf[ni] = *(const half8*)((const char*)Bs + r * 128 + s * 16);
                }
                #pragma unroll
                for (int mi = 0; mi < 4; ++mi)
                    #pragma unroll
                    for (int ni = 0; ni < 4; ++ni)
                        acc[mi][ni] = __builtin_amdgcn_mfma_f32_16x16x32_f16(af[mi], bf[ni], acc[mi][ni], 0, 0, 0);
            }
            __syncthreads();
        }
        #pragma unroll
        for (int ni = 0; ni < 4; ++ni) {
            int col = nb + wn * 64 + ni * 16 + c16;
            #pragma unroll
            for (int mi = 0; mi < 4; ++mi) {
                #pragma unroll
                for (int j = 0; j < 4; ++j) {
                    float v = acc[mi][ni][j];
                    float old0 = v0r[mi][j];
                    v1r[mi][j] = __builtin_amdgcn_fmed3f(v, old0, v1r[mi][j]);
                    bool lt = v < old0;
                    v0r[mi][j] = lt ? v : old0;
                    i0r[mi][j] = lt ? col : i0r[mi][j];
                }
            }
        }
    }

    #pragma unroll
    for (int off = 1; off < 16; off <<= 1) {
        #pragma unroll
        for (int mi = 0; mi < 4; ++mi)
            #pragma unroll
            for (int j = 0; j < 4; ++j) {
                float ov0 = __shfl_xor(v0r[mi][j], off);
                int   oi0 = __shfl_xor(i0r[mi][j], off);
                float ov1 = __shfl_xor(v1r[mi][j], off);
                float nv1 = fminf(fmaxf(v0r[mi][j], ov0), fminf(v1r[mi][j], ov1));
                bool take = (ov0 < v0r[mi][j]) || (ov0 == v0r[mi][j] && oi0 < i0r[mi][j]);
                v0r[mi][j] = take ? ov0 : v0r[mi][j];
                i0r[mi][j] = take ? oi0 : i0r[mi][j];
                v1r[mi][j] = nv1;
            }
    }
    if (c16 == 0) {
        #pragma unroll
        for (int mi = 0; mi < 4; ++mi)
            #pragma unroll
            for (int j = 0; j < 4; ++j) {
                int r = wm * 64 + mi * 16 + q4 * 4 + j;
                lds_v0[r][wn] = v0r[mi][j];
                lds_i0[r][wn] = i0r[mi][j];
                lds_v1[r][wn] = v1r[mi][j];
            }
    }
    __syncthreads();
    if (tid < BM) {
        float a0 = lds_v0[tid][0], b0 = lds_v0[tid][1];
        int   ai = lds_i0[tid][0], bi = lds_i0[tid][1];
        float a1 = lds_v1[tid][0], b1 = lds_v1[tid][1];
        float v1 = fminf(fmaxf(a0, b0), fminf(a1, b1));
        bool take = (b0 < a0) || (b0 == a0 && bi < ai);
        float v0 = take ? b0 : a0;
        int   i0 = take ? bi : ai;
        size_t o = (size_t)split * BT_N + m0 + tid;
        ws_v0[o] = v0; ws_i0[o] = i0; ws_v1[o] = v1;
    }
}

// ---------------- Kernel M: merge splits, flag close calls ----------------
__global__ __launch_bounds__(256) void vq_merge(
    const float* __restrict__ ws_v0, const int* __restrict__ ws_i0, const float* __restrict__ ws_v1,
    int* __restrict__ out_idx, int* __restrict__ list, unsigned int* __restrict__ counter)
{
    int q = blockIdx.x * 256 + threadIdx.x;
    float v0 = ws_v0[q]; int i0 = ws_i0[q]; float v1 = ws_v1[q];
    #pragma unroll
    for (int s = 1; s < 4; ++s) {
        size_t o = (size_t)s * BT_N + q;
        float sv0 = ws_v0[o]; int si0 = ws_i0[o]; float sv1 = ws_v1[o];
        v1 = fminf(fmaxf(v0, sv0), fminf(v1, sv1));
        bool take = (sv0 < v0) || (sv0 == v0 && si0 < i0);
        if (take) { v0 = sv0; i0 = si0; }
    }
    if (v1 - v0 < W_FLAG) {
        unsigned int pos = atomicAdd(counter, 1u);
        if (pos < CAP) { list[pos] = q; out_idx[q] = -1; }
        else           { out_idx[q] = i0; }       // graceful degradation (never hit)
    } else {
        out_idx[q] = i0;
    }
}

// ---------------- Kernel R: hi/lo fp16 MFMA rescan of flagged rows over all codes --
// grid (CAP/64 M-tiles, NSPLIT code-splits of 512) x 256 threads (4 waves x 32 cols)
__global__ __launch_bounds__(256) void vq_rescan(
    const float* __restrict__ X,
    const _Float16* __restrict__ Ch, const _Float16* __restrict__ Cl,
    const float* __restrict__ cnormP,
    const int* __restrict__ list, const unsigned int* __restrict__ counter,
    float* __restrict__ rs_v0, int* __restrict__ rs_i0,
    float* __restrict__ rs_v1, int* __restrict__ rs_i1)
{
    int mcnt = min((int)*counter, CAP);
    const int m0 = blockIdx.x * 64;
    if (m0 >= mcnt) return;
    const int split = blockIdx.y;
    const int nbase = split * 512;

    __shared__ _Float16 Ah[64][72], Al[64][72];     // +8 pad: frag-read 2-way max
    __shared__ _Float16 Bh[128][72], Bl[128][72];
    __shared__ int   qr[64];
    __shared__ float e_v0[64][4]; __shared__ int e_i0[64][4];
    __shared__ float e_v1[64][4]; __shared__ int e_i1[64][4];

    const int tid  = threadIdx.x;
    const int lane = tid & 63;
    const int w    = tid >> 6;
    const int c16  = lane & 15;
    const int q4   = lane >> 4;

    if (tid < 64) qr[tid] = list[min(m0 + tid, mcnt - 1)];
    __syncthreads();

    // A staging map: thread -> (row, 16-float chunk)
    const int ar = tid >> 2;
    const int ac = (tid & 3) << 4;
    const size_t asrc_row = (size_t)qr[ar] * DDIM;

    float t2v0[4][4], t2v1[4][4]; int t2i0[4][4], t2i1[4][4];
    #pragma unroll
    for (int a = 0; a < 4; a++)
        #pragma unroll
        for (int b = 0; b < 4; b++) {
            t2v0[a][b] = 3e38f; t2v1[a][b] = 3e38f;
            t2i0[a][b] = 0x7fffffff; t2i1[a][b] = 0x7fffffff;
        }

    for (int nt = 0; nt < 4; ++nt) {
        const int nb = nbase + nt * 128;
        fx4 acc[4][2];
        #pragma unroll
        for (int mi = 0; mi < 4; ++mi)
            #pragma unroll
            for (int ni = 0; ni < 2; ++ni) acc[mi][ni] = (fx4){0.f, 0.f, 0.f, 0.f};

        for (int kb = 0; kb < DDIM; kb += 64) {
            // stage A (hi/lo from fp32 X, gathered rows)
            {
                const float4* s4 = (const float4*)(X + asrc_row + kb + ac);
                float4 f0 = s4[0], f1 = s4[1], f2 = s4[2], f3 = s4[3];
                float fv[16] = {f0.x,f0.y,f0.z,f0.w, f1.x,f1.y,f1.z,f1.w,
                                f2.x,f2.y,f2.z,f2.w, f3.x,f3.y,f3.z,f3.w};
                half8 h0, l0, h1, l1;
                #pragma unroll
                for (int i = 0; i < 8; ++i) {
                    _Float16 hh = (_Float16)fv[i];
                    h0[i] = hh; l0[i] = (_Float16)(fv[i] - (float)hh);
                    _Float16 hh2 = (_Float16)fv[8+i];
                    h1[i] = hh2; l1[i] = (_Float16)(fv[8+i] - (float)hh2);
                }
                *(half8*)&Ah[ar][ac]     = h0;  *(half8*)&Ah[ar][ac + 8] = h1;
                *(half8*)&Al[ar][ac]     = l0;  *(half8*)&Al[ar][ac + 8] = l1;
            }
            // stage B (hi/lo fp16 codebook, contiguous rows)
            #pragma unroll
            for (int g = 0; g < 4; ++g) {
                int li = g * 256 + tid;
                int br = li >> 3, bs = (li & 7) << 3;
                size_t src = (size_t)(nb + br) * DDIM + kb + bs;
                *(half8*)&Bh[br][bs] = *(const half8*)(Ch + src);
                *(half8*)&Bl[br][bs] = *(const half8*)(Cl + src);
            }
            __syncthreads();
            #pragma unroll
            for (int kk = 0; kk < 2; ++kk) {
                const int col = kk * 32 + q4 * 8;
                half8 ahf[4], alf[4], bhf[2], blf[2];
                #pragma unroll
                for (int mi = 0; mi < 4; ++mi) {
                    ahf[mi] = *(const half8*)&Ah[mi * 16 + c16][col];
                    alf[mi] = *(const half8*)&Al[mi * 16 + c16][col];
                }
                #pragma unroll
                for (int ni = 0; ni < 2; ++ni) {
                    int br = w * 32 + ni * 16 + c16;
                    bhf[ni] = *(const half8*)&Bh[br][col];
                    blf[ni] = *(const half8*)&Bl[br][col];
                }
                #pragma unroll
                for (int mi = 0; mi < 4; ++mi)
                    #pragma unroll
                    for (int ni = 0; ni < 2; ++ni) {
                        acc[mi][ni] = __builtin_amdgcn_mfma_f32_16x16x32_f16(ahf[mi], bhf[ni], acc[mi][ni], 0, 0, 0);
                        acc[mi][ni] = __builtin_amdgcn_mfma_f32_16x16x32_f16(ahf[mi], blf[ni], acc[mi][ni], 0, 0, 0);
                        acc[mi][ni] = __builtin_amdgcn_mfma_f32_16x16x32_f16(alf[mi], bhf[ni], acc[mi][ni], 0, 0, 0);
                    }
            }
            __syncthreads();
        }
        // epilogue: add cnorm, update per-lane top-2
        #pragma unroll
        for (int ni = 0; ni < 2; ++ni) {
            int code = nb + w * 32 + ni * 16 + c16;
            float cn = cnormP[code];
            #pragma unroll
            for (int mi = 0; mi < 4; ++mi)
                #pragma unroll
                for (int j = 0; j < 4; ++j)
                    t2_update(t2v0[mi][j], t2i0[mi][j], t2v1[mi][j], t2i1[mi][j],
                              acc[mi][ni][j] + cn, code);
        }
    }

    // butterfly across the 16 cols of each quad-row group
    #pragma unroll
    for (int off = 1; off < 16; off <<= 1) {
        #pragma unroll
        for (int mi = 0; mi < 4; ++mi)
            #pragma unroll
            for (int j = 0; j < 4; ++j) {
                float ov0 = __shfl_xor(t2v0[mi][j], off);
                int   oi0 = __shfl_xor(t2i0[mi][j], off);
                float ov1 = __shfl_xor(t2v1[mi][j], off);
                int   oi1 = __shfl_xor(t2i1[mi][j], off);
                t2_merge(t2v0[mi][j], t2i0[mi][j], t2v1[mi][j], t2i1[mi][j],
                         ov0, oi0, ov1, oi1);
            }
    }
    if (c16 == 0) {
        #pragma unroll
        for (int mi = 0; mi < 4; ++mi)
            #pragma unroll
            for (int j = 0; j < 4; ++j) {
                int r = mi * 16 + q4 * 4 + j;
                e_v0[r][w] = t2v0[mi][j]; e_i0[r][w] = t2i0[mi][j];
                e_v1[r][w] = t2v1[mi][j]; e_i1[r][w] = t2i1[mi][j];
            }
    }
    __syncthreads();
    if (tid < 64 && m0 + tid < mcnt) {
        float v0 = e_v0[tid][0], v1 = e_v1[tid][0];
        int   i0 = e_i0[tid][0], i1 = e_i1[tid][0];
        #pragma unroll
        for (int wc = 1; wc < 4; ++wc)
            t2_merge(v0, i0, v1, i1, e_v0[tid][wc], e_i0[tid][wc], e_v1[tid][wc], e_i1[tid][wc]);
        size_t o = (size_t)split * CAP + m0 + tid;
        rs_v0[o] = v0; rs_i0[o] = i0; rs_v1[o] = v1; rs_i1[o] = i1;
    }
}

// ---------------- Kernel M2: merge rescan splits; rare inline fp64 verdict ------
__global__ __launch_bounds__(256) void vq_merge2(
    const float* __restrict__ X, const float* __restrict__ CB,
    const int* __restrict__ list, const unsigned int* __restrict__ counter,
    const float* __restrict__ rs_v0, const int* __restrict__ rs_i0,
    const float* __restrict__ rs_v1, const int* __restrict__ rs_i1,
    int* __restrict__ out_idx)
{
    int m = blockIdx.x * 256 + threadIdx.x;
    int cnt = min((int)*counter, CAP);
    if (m >= cnt) return;
    int q = list[m];
    float v0 = 3e38f, v1 = 3e38f; int i0 = 0x7fffffff, i1 = 0x7fffffff;
    #pragma unroll
    for (int s = 0; s < NSPLIT; ++s) {
        size_t o = (size_t)s * CAP + m;
        t2_merge(v0, i0, v1, i1, rs_v0[o], rs_i0[o], rs_v1[o], rs_i1[o]);
    }
    int pick = i0;
    if (v1 - v0 < W2) {   // refined scores too close -> exact fp64 on the pair
        const float* xr  = X  + (size_t)q  * DDIM;
        const float* c0p = CB + (size_t)i0 * DDIM;
        const float* c1p = CB + (size_t)i1 * DDIM;
        double d0 = 0.0, d1 = 0.0;
        for (int d = 0; d < DDIM; ++d) {
            double xv = (double)xr[d];
            double e0 = xv - (double)c0p[d]; d0 = fma(e0, e0, d0);
            double e1 = xv - (double)c1p[d]; d1 = fma(e1, e1, d1);
        }
        bool tb = (d1 < d0) || (d1 == d0 && i1 < i0);
        pick = tb ? i1 : i0;
    }
    out_idx[q] = pick;
}

// ---------------- Kernel G: gather codebook rows ----------------
__global__ __launch_bounds__(128) void vq_gather(
    const float* __restrict__ CB, const int* __restrict__ out_idx,
    float* __restrict__ out)
{
    int q = blockIdx.x;
    int idx = out_idx[q];
    int t = threadIdx.x;
    ((float4*)(out + (size_t)q * DDIM))[t] = ((const float4*)(CB + (size_t)idx * DDIM))[t];
}

// ---------------- launcher ----------------
extern "C" void kernel_launch(void* const* d_in, const int* in_sizes, int n_in,
                              void* d_out, int out_size, void* d_ws, size_t ws_size,
                              hipStream_t stream) {
    const float* X  = (const float*)d_in[0];   // [32768,512]
    const float* CB = (const float*)d_in[1];   // [4096,512]
    float* out = (float*)d_out;

    char* ws = (char*)d_ws;
    _Float16* Xh       = (_Float16*)(ws + OFF_XH);
    _Float16* Ch       = (_Float16*)(ws + OFF_CH);
    _Float16* Cl       = (_Float16*)(ws + OFF_CL);
    float*    cnormP   = (float*)(ws + OFF_CNP);
    double*   cnorm_dp = (double*)(ws + OFF_CND);
    float*    ws_v0    = (float*)(ws + OFF_V0);
    int*      ws_i0    = (int*)(ws + OFF_I0);
    float*    ws_v1    = (float*)(ws + OFF_V1);
    int*      out_idx  = (int*)(ws + OFF_OIDX);
    int*      list     = (int*)(ws + OFF_LIST);
    unsigned int* counter = (unsigned int*)(ws + OFF_CNT);
    float*    rs_v0    = (float*)(ws + OFF_RSV0);
    int*      rs_i0    = (int*)(ws + OFF_RSI0);
    float*    rs_v1    = (float*)(ws + OFF_RSV1);
    int*      rs_i1    = (int*)(ws + OFF_RSI1);

    hipMemsetAsync(counter, 0, 4, stream);
    vq_cvt_x<<<2048, 256, 0, stream>>>(X, Xh, BT_N * DDIM / 8);
    vq_cvt_cb<<<KCB, 64, 0, stream>>>(CB, Ch, Cl, cnormP, cnorm_dp);
    vq_gemm<<<1024, 256, 0, stream>>>(Xh, Ch, cnormP, ws_v0, ws_i0, ws_v1);
    vq_merge<<<BT_N / 256, 256, 0, stream>>>(ws_v0, ws_i0, ws_v1, out_idx, list, counter);
    vq_rescan<<<dim3(CAP / 64, NSPLIT), 256, 0, stream>>>(X, Ch, Cl, cnormP, list, counter,
                                                          rs_v0, rs_i0, rs_v1, rs_i1);
    vq_merge2<<<CAP / 256, 256, 0, stream>>>(X, CB, list, counter,
                                             rs_v0, rs_i0, rs_v1, rs_i1, out_idx);
    vq_gather<<<BT_N, 128, 0, stream>>>(CB, out_idx, out);
}

// Round 3
// 474.902 us; speedup vs baseline: 2.0010x; 1.0302x over previous
//
#include <hip/hip_runtime.h>
#include <hip/hip_fp16.h>

// Problem constants
#define BT_N   32768   // B*T queries
#define DDIM   512
#define KCB    4096
#define W_FLAG 0.28f   // fp16-pass gap window (~18 sigma incl. key-quantization bias)
#define W2     0.01f   // refined-pass gap window (20x worst-case refined error)
#define CAP    8192    // max flagged queries handled (expected ~900)
#define NSPLIT 8       // rescan code splits (512 codes each)

typedef _Float16 half8 __attribute__((ext_vector_type(8)));
typedef float    fx4   __attribute__((ext_vector_type(4)));

// ---------------- workspace layout ----------------
static constexpr size_t OFF_XH   = 0;                                // fp16 inputs          32 MB
static constexpr size_t OFF_CH   = OFF_XH   + (size_t)BT_N*DDIM*2;   // fp16 hi(-2c)          4 MB
static constexpr size_t OFF_CL   = OFF_CH   + (size_t)KCB*DDIM*2;    // fp16 lo(-2c)          4 MB
static constexpr size_t OFF_CNP  = OFF_CL   + (size_t)KCB*DDIM*2;    // float  cnorm+1024    16 KB
static constexpr size_t OFF_CND  = OFF_CNP  + (size_t)KCB*4;         // double cnorm         32 KB
static constexpr size_t OFF_V0   = OFF_CND  + (size_t)KCB*8;         // per (split,q) top1 val
static constexpr size_t OFF_I0   = OFF_V0   + (size_t)4*BT_N*4;      // per (split,q) top1 idx
static constexpr size_t OFF_V1   = OFF_I0   + (size_t)4*BT_N*4;      // per (split,q) 2nd val
static constexpr size_t OFF_OIDX = OFF_V1   + (size_t)4*BT_N*4;      // final idx
static constexpr size_t OFF_LIST = OFF_OIDX + (size_t)BT_N*4;        // flagged query list
static constexpr size_t OFF_CNT  = OFF_LIST + (size_t)CAP*4;         // flagged counter
static constexpr size_t OFF_RSV0 = OFF_CNT  + 64;                    // rescan per-split top2
static constexpr size_t OFF_RSI0 = OFF_RSV0 + (size_t)NSPLIT*CAP*4;
static constexpr size_t OFF_RSV1 = OFF_RSI0 + (size_t)NSPLIT*CAP*4;
static constexpr size_t OFF_RSI1 = OFF_RSV1 + (size_t)NSPLIT*CAP*4;

// ---------------- async 16B global->LDS ----------------
__device__ __forceinline__ void async16(const void* g, void* l) {
    __builtin_amdgcn_global_load_lds(
        (const __attribute__((address_space(1))) unsigned int*)g,
        (__attribute__((address_space(3))) unsigned int*)l,
        16, 0, 0);
}

// ---------------- top-2 helpers (smaller-index tie-break, np.argmin semantics) ---
__device__ __forceinline__ void t2_update(float& v0, int& i0, float& v1, int& i1,
                                          float v, int idx) {
    bool t0 = (v < v0) || (v == v0 && idx < i0);
    bool t1 = (v < v1) || (v == v1 && idx < i1);
    float nv1 = t0 ? v0 : (t1 ? v : v1);
    int   ni1 = t0 ? i0 : (t1 ? idx : i1);
    v1 = nv1; i1 = ni1;
    v0 = t0 ? v : v0;
    i0 = t0 ? idx : i0;
}
__device__ __forceinline__ void t2_merge(float& v0, int& i0, float& v1, int& i1,
                                         float ov0, int oi0, float ov1, int oi1) {
    bool oa = (ov0 < v0) || (ov0 == v0 && oi0 < i0);
    float w0 = oa ? ov0 : v0;  int wi0 = oa ? oi0 : i0;
    float l0 = oa ? v0 : ov0;  int li0 = oa ? i0 : oi0;
    float ws = oa ? ov1 : v1;  int wsi = oa ? oi1 : i1;
    bool sb = (l0 < ws) || (l0 == ws && li0 < wsi);
    v0 = w0; i0 = wi0;
    v1 = sb ? l0 : ws; i1 = sb ? li0 : wsi;
}

// ---------------- K_x: convert inputs fp32 -> fp16 ----------------
__global__ __launch_bounds__(256) void vq_cvt_x(const float* __restrict__ X,
                                                _Float16* __restrict__ Xh, int n8) {
    int i = blockIdx.x * 256 + threadIdx.x;
    int stride = gridDim.x * 256;
    for (; i < n8; i += stride) {
        float4 a = ((const float4*)X)[(size_t)i*2];
        float4 b = ((const float4*)X)[(size_t)i*2 + 1];
        half8 h;
        h[0]=(_Float16)a.x; h[1]=(_Float16)a.y; h[2]=(_Float16)a.z; h[3]=(_Float16)a.w;
        h[4]=(_Float16)b.x; h[5]=(_Float16)b.y; h[6]=(_Float16)b.z; h[7]=(_Float16)b.w;
        ((half8*)Xh)[i] = h;
    }
}

// ---------------- K_cb: codebook -> fp16 hi/lo of (-2c), cnorms (4 rows/block) ---
__global__ __launch_bounds__(256) void vq_cvt_cb(const float* __restrict__ CB,
                                                 _Float16* __restrict__ Ch,
                                                 _Float16* __restrict__ Cl,
                                                 float* __restrict__ cnormP,
                                                 double* __restrict__ cnorm_dp) {
    int r = blockIdx.x * 4 + (threadIdx.x >> 6);
    int t = threadIdx.x & 63;
    const float* row = CB + (size_t)r * DDIM;
    float4 a = ((const float4*)row)[t*2];
    float4 b = ((const float4*)row)[t*2 + 1];
    double s = (double)a.x*a.x + (double)a.y*a.y + (double)a.z*a.z + (double)a.w*a.w
             + (double)b.x*b.x + (double)b.y*b.y + (double)b.z*b.z + (double)b.w*b.w;
    float f[8] = {-2.0f*a.x, -2.0f*a.y, -2.0f*a.z, -2.0f*a.w,
                  -2.0f*b.x, -2.0f*b.y, -2.0f*b.z, -2.0f*b.w};
    half8 h, l;
    #pragma unroll
    for (int i = 0; i < 8; ++i) {
        _Float16 hh = (_Float16)f[i];
        h[i] = hh;
        l[i] = (_Float16)(f[i] - (float)hh);
    }
    ((half8*)(Ch + (size_t)r * DDIM))[t] = h;
    ((half8*)(Cl + (size_t)r * DDIM))[t] = l;
    #pragma unroll
    for (int off = 1; off < 64; off <<= 1) s += __shfl_xor(s, off);
    if (t == 0) { cnorm_dp[r] = s; cnormP[r] = (float)(s + 1024.0); }
}

// ---------------- Kernel A: fp16 MFMA GEMM + keyed top-2 tracking ----------------
// Scores d2p = cnorm+1024-2x.c > 0, so float bit order == numeric order. Low 5
// mantissa bits carry idx5=(nt<<2)|ni (code order is monotone in idx5: adjacent
// (nt,ni) codes differ by >=16 > c16 range). Quantization <= 2^-7, absorbed by
// W_FLAG. Update = and_or + med3 + min: 3 VALU, no vcc chain.
#define BM 128
#define BN 128
#define BK 64
__global__ __launch_bounds__(256, 2) void vq_gemm(
    const _Float16* __restrict__ Xh, const _Float16* __restrict__ Ch,
    const float* __restrict__ cnormP,
    float* __restrict__ ws_v0, int* __restrict__ ws_i0, float* __restrict__ ws_v1)
{
    __shared__ _Float16 As[BM * BK];
    __shared__ _Float16 Bs[BN * BK];
    __shared__ float lds_v0[BM][2];
    __shared__ int   lds_i0[BM][2];
    __shared__ float lds_v1[BM][2];

    const int tid   = threadIdx.x;
    const int lane  = tid & 63;
    const int w     = tid >> 6;
    const int wm    = w >> 1, wn = w & 1;
    const int qblk  = blockIdx.x >> 2;
    const int split = blockIdx.x & 3;
    const int m0    = qblk * BM;
    const int nbase = split * 1024;
    const int c16   = lane & 15;
    const int q4    = lane >> 4;

    // packed-key running top-2 per owned (mi,j) row slot
    float k0r[4][4], k1r[4][4];
    #pragma unroll
    for (int a = 0; a < 4; a++)
        #pragma unroll
        for (int b = 0; b < 4; b++) { k0r[a][b] = 3e38f; k1r[a][b] = 3e38f; }

    int srow[4], scol[4], sdst[4];
    #pragma unroll
    for (int g = 0; g < 4; ++g) {
        int li = g * 256 + tid;
        int row = li >> 3, slot = li & 7;
        srow[g] = row;
        scol[g] = ((slot ^ (row & 7)) << 3);
        sdst[g] = li << 4;
    }

    for (int nt = 0; nt < 8; ++nt) {
        const int nb = nbase + nt * BN;
        fx4 acc[4][4];
        #pragma unroll
        for (int ni = 0; ni < 4; ++ni) {
            float cn = cnormP[nb + wn * 64 + ni * 16 + c16];
            #pragma unroll
            for (int mi = 0; mi < 4; ++mi) acc[mi][ni] = (fx4){cn, cn, cn, cn};
        }
        for (int kb = 0; kb < DDIM; kb += BK) {
            #pragma unroll
            for (int g = 0; g < 4; ++g)
                async16(Xh + (size_t)(m0 + srow[g]) * DDIM + kb + scol[g], (char*)As + sdst[g]);
            #pragma unroll
            for (int g = 0; g < 4; ++g)
                async16(Ch + (size_t)(nb + srow[g]) * DDIM + kb + scol[g], (char*)Bs + sdst[g]);
            __syncthreads();
            #pragma unroll
            for (int kk = 0; kk < 2; ++kk) {
                half8 af[4], bf[4];
                #pragma unroll
                for (int mi = 0; mi < 4; ++mi) {
                    int r = wm * 64 + mi * 16 + c16;
                    int s = (kk * 4 + q4) ^ (r & 7);
                    af[mi] = *(const half8*)((const char*)As + r * 128 + s * 16);
                }
                #pragma unroll
                for (int ni = 0; ni < 4; ++ni) {
                    int r = wn * 64 + ni * 16 + c16;
                    int s = (kk * 4 + q4) ^ (r & 7);
                    bf[ni] = *(const half8*)((const char*)Bs + r * 128 + s * 16);
                }
                #pragma unroll
                for (int mi = 0; mi < 4; ++mi)
                    #pragma unroll
                    for (int ni = 0; ni < 4; ++ni)
                        acc[mi][ni] = __builtin_amdgcn_mfma_f32_16x16x32_f16(af[mi], bf[ni], acc[mi][ni], 0, 0, 0);
            }
            __syncthreads();
        }
        // keyed epilogue: 3 VALU per value, no vcc serialization
        #pragma unroll
        for (int ni = 0; ni < 4; ++ni) {
            const int idx5 = (nt << 2) | ni;
            #pragma unroll
            for (int mi = 0; mi < 4; ++mi) {
                #pragma unroll
                for (int j = 0; j < 4; ++j) {
                    float key = __int_as_float(
                        (__float_as_int(acc[mi][ni][j]) & 0xFFFFFFE0) | idx5);
                    k1r[mi][j] = __builtin_amdgcn_fmed3f(key, k0r[mi][j], k1r[mi][j]);
                    k0r[mi][j] = fminf(k0r[mi][j], key);
                }
            }
        }
    }

    // unpack keys -> (v0, col, v1) then butterfly across the 16 lanes
    float v0r[4][4], v1r[4][4]; int i0r[4][4];
    #pragma unroll
    for (int mi = 0; mi < 4; ++mi)
        #pragma unroll
        for (int j = 0; j < 4; ++j) {
            int b = __float_as_int(k0r[mi][j]);
            int idx5 = b & 31;
            i0r[mi][j] = nbase + (idx5 >> 2) * BN + wn * 64 + (idx5 & 3) * 16 + c16;
            v0r[mi][j] = __int_as_float(b & 0xFFFFFFE0);
            v1r[mi][j] = __int_as_float(__float_as_int(k1r[mi][j]) & 0xFFFFFFE0);
        }
    #pragma unroll
    for (int off = 1; off < 16; off <<= 1) {
        #pragma unroll
        for (int mi = 0; mi < 4; ++mi)
            #pragma unroll
            for (int j = 0; j < 4; ++j) {
                float ov0 = __shfl_xor(v0r[mi][j], off);
                int   oi0 = __shfl_xor(i0r[mi][j], off);
                float ov1 = __shfl_xor(v1r[mi][j], off);
                float nv1 = fminf(fmaxf(v0r[mi][j], ov0), fminf(v1r[mi][j], ov1));
                bool take = (ov0 < v0r[mi][j]) || (ov0 == v0r[mi][j] && oi0 < i0r[mi][j]);
                v0r[mi][j] = take ? ov0 : v0r[mi][j];
                i0r[mi][j] = take ? oi0 : i0r[mi][j];
                v1r[mi][j] = nv1;
            }
    }
    if (c16 == 0) {
        #pragma unroll
        for (int mi = 0; mi < 4; ++mi)
            #pragma unroll
            for (int j = 0; j < 4; ++j) {
                int r = wm * 64 + mi * 16 + q4 * 4 + j;
                lds_v0[r][wn] = v0r[mi][j];
                lds_i0[r][wn] = i0r[mi][j];
                lds_v1[r][wn] = v1r[mi][j];
            }
    }
    __syncthreads();
    if (tid < BM) {
        float a0 = lds_v0[tid][0], b0 = lds_v0[tid][1];
        int   ai = lds_i0[tid][0], bi = lds_i0[tid][1];
        float a1 = lds_v1[tid][0], b1 = lds_v1[tid][1];
        float v1 = fminf(fmaxf(a0, b0), fminf(a1, b1));
        bool take = (b0 < a0) || (b0 == a0 && bi < ai);
        float v0 = take ? b0 : a0;
        int   i0 = take ? bi : ai;
        size_t o = (size_t)split * BT_N + m0 + tid;
        ws_v0[o] = v0; ws_i0[o] = i0; ws_v1[o] = v1;
    }
}

// ---------------- Kernel M: merge splits, flag close calls ----------------
__global__ __launch_bounds__(256) void vq_merge(
    const float* __restrict__ ws_v0, const int* __restrict__ ws_i0, const float* __restrict__ ws_v1,
    int* __restrict__ out_idx, int* __restrict__ list, unsigned int* __restrict__ counter)
{
    int q = blockIdx.x * 256 + threadIdx.x;
    float v0 = ws_v0[q]; int i0 = ws_i0[q]; float v1 = ws_v1[q];
    #pragma unroll
    for (int s = 1; s < 4; ++s) {
        size_t o = (size_t)s * BT_N + q;
        float sv0 = ws_v0[o]; int si0 = ws_i0[o]; float sv1 = ws_v1[o];
        v1 = fminf(fmaxf(v0, sv0), fminf(v1, sv1));
        bool take = (sv0 < v0) || (sv0 == v0 && si0 < i0);
        if (take) { v0 = sv0; i0 = si0; }
    }
    if (v1 - v0 < W_FLAG) {
        unsigned int pos = atomicAdd(counter, 1u);
        if (pos < CAP) { list[pos] = q; out_idx[q] = -1; }
        else           { out_idx[q] = i0; }       // graceful degradation (never hit)
    } else {
        out_idx[q] = i0;
    }
}

// ---------------- Kernel R: hi/lo fp16 MFMA rescan of flagged rows over all codes --
__global__ __launch_bounds__(256) void vq_rescan(
    const float* __restrict__ X,
    const _Float16* __restrict__ Ch, const _Float16* __restrict__ Cl,
    const float* __restrict__ cnormP,
    const int* __restrict__ list, const unsigned int* __restrict__ counter,
    float* __restrict__ rs_v0, int* __restrict__ rs_i0,
    float* __restrict__ rs_v1, int* __restrict__ rs_i1)
{
    int mcnt = min((int)*counter, CAP);
    const int m0 = blockIdx.x * 64;
    if (m0 >= mcnt) return;
    const int split = blockIdx.y;
    const int nbase = split * 512;

    __shared__ _Float16 Ah[64][72], Al[64][72];
    __shared__ _Float16 Bh[128][72], Bl[128][72];
    __shared__ int   qr[64];
    __shared__ float e_v0[64][4]; __shared__ int e_i0[64][4];
    __shared__ float e_v1[64][4]; __shared__ int e_i1[64][4];

    const int tid  = threadIdx.x;
    const int lane = tid & 63;
    const int w    = tid >> 6;
    const int c16  = lane & 15;
    const int q4   = lane >> 4;

    if (tid < 64) qr[tid] = list[min(m0 + tid, mcnt - 1)];
    __syncthreads();

    const int ar = tid >> 2;
    const int ac = (tid & 3) << 4;
    const size_t asrc_row = (size_t)qr[ar] * DDIM;

    float t2v0[4][4], t2v1[4][4]; int t2i0[4][4], t2i1[4][4];
    #pragma unroll
    for (int a = 0; a < 4; a++)
        #pragma unroll
        for (int b = 0; b < 4; b++) {
            t2v0[a][b] = 3e38f; t2v1[a][b] = 3e38f;
            t2i0[a][b] = 0x7fffffff; t2i1[a][b] = 0x7fffffff;
        }

    for (int nt = 0; nt < 4; ++nt) {
        const int nb = nbase + nt * 128;
        fx4 acc[4][2];
        #pragma unroll
        for (int mi = 0; mi < 4; ++mi)
            #pragma unroll
            for (int ni = 0; ni < 2; ++ni) acc[mi][ni] = (fx4){0.f, 0.f, 0.f, 0.f};

        for (int kb = 0; kb < DDIM; kb += 64) {
            {
                const float4* s4 = (const float4*)(X + asrc_row + kb + ac);
                float4 f0 = s4[0], f1 = s4[1], f2 = s4[2], f3 = s4[3];
                float fv[16] = {f0.x,f0.y,f0.z,f0.w, f1.x,f1.y,f1.z,f1.w,
                                f2.x,f2.y,f2.z,f2.w, f3.x,f3.y,f3.z,f3.w};
                half8 h0, l0, h1, l1;
                #pragma unroll
                for (int i = 0; i < 8; ++i) {
                    _Float16 hh = (_Float16)fv[i];
                    h0[i] = hh; l0[i] = (_Float16)(fv[i] - (float)hh);
                    _Float16 hh2 = (_Float16)fv[8+i];
                    h1[i] = hh2; l1[i] = (_Float16)(fv[8+i] - (float)hh2);
                }
                *(half8*)&Ah[ar][ac]     = h0;  *(half8*)&Ah[ar][ac + 8] = h1;
                *(half8*)&Al[ar][ac]     = l0;  *(half8*)&Al[ar][ac + 8] = l1;
            }
            #pragma unroll
            for (int g = 0; g < 4; ++g) {
                int li = g * 256 + tid;
                int br = li >> 3, bs = (li & 7) << 3;
                size_t src = (size_t)(nb + br) * DDIM + kb + bs;
                *(half8*)&Bh[br][bs] = *(const half8*)(Ch + src);
                *(half8*)&Bl[br][bs] = *(const half8*)(Cl + src);
            }
            __syncthreads();
            #pragma unroll
            for (int kk = 0; kk < 2; ++kk) {
                const int col = kk * 32 + q4 * 8;
                half8 ahf[4], alf[4], bhf[2], blf[2];
                #pragma unroll
                for (int mi = 0; mi < 4; ++mi) {
                    ahf[mi] = *(const half8*)&Ah[mi * 16 + c16][col];
                    alf[mi] = *(const half8*)&Al[mi * 16 + c16][col];
                }
                #pragma unroll
                for (int ni = 0; ni < 2; ++ni) {
                    int br = w * 32 + ni * 16 + c16;
                    bhf[ni] = *(const half8*)&Bh[br][col];
                    blf[ni] = *(const half8*)&Bl[br][col];
                }
                #pragma unroll
                for (int mi = 0; mi < 4; ++mi)
                    #pragma unroll
                    for (int ni = 0; ni < 2; ++ni) {
                        acc[mi][ni] = __builtin_amdgcn_mfma_f32_16x16x32_f16(ahf[mi], bhf[ni], acc[mi][ni], 0, 0, 0);
                        acc[mi][ni] = __builtin_amdgcn_mfma_f32_16x16x32_f16(ahf[mi], blf[ni], acc[mi][ni], 0, 0, 0);
                        acc[mi][ni] = __builtin_amdgcn_mfma_f32_16x16x32_f16(alf[mi], bhf[ni], acc[mi][ni], 0, 0, 0);
                    }
            }
            __syncthreads();
        }
        #pragma unroll
        for (int ni = 0; ni < 2; ++ni) {
            int code = nb + w * 32 + ni * 16 + c16;
            float cn = cnormP[code];
            #pragma unroll
            for (int mi = 0; mi < 4; ++mi)
                #pragma unroll
                for (int j = 0; j < 4; ++j)
                    t2_update(t2v0[mi][j], t2i0[mi][j], t2v1[mi][j], t2i1[mi][j],
                              acc[mi][ni][j] + cn, code);
        }
    }

    #pragma unroll
    for (int off = 1; off < 16; off <<= 1) {
        #pragma unroll
        for (int mi = 0; mi < 4; ++mi)
            #pragma unroll
            for (int j = 0; j < 4; ++j) {
                float ov0 = __shfl_xor(t2v0[mi][j], off);
                int   oi0 = __shfl_xor(t2i0[mi][j], off);
                float ov1 = __shfl_xor(t2v1[mi][j], off);
                int   oi1 = __shfl_xor(t2i1[mi][j], off);
                t2_merge(t2v0[mi][j], t2i0[mi][j], t2v1[mi][j], t2i1[mi][j],
                         ov0, oi0, ov1, oi1);
            }
    }
    if (c16 == 0) {
        #pragma unroll
        for (int mi = 0; mi < 4; ++mi)
            #pragma unroll
            for (int j = 0; j < 4; ++j) {
                int r = mi * 16 + q4 * 4 + j;
                e_v0[r][w] = t2v0[mi][j]; e_i0[r][w] = t2i0[mi][j];
                e_v1[r][w] = t2v1[mi][j]; e_i1[r][w] = t2i1[mi][j];
            }
    }
    __syncthreads();
    if (tid < 64 && m0 + tid < mcnt) {
        float v0 = e_v0[tid][0], v1 = e_v1[tid][0];
        int   i0 = e_i0[tid][0], i1 = e_i1[tid][0];
        #pragma unroll
        for (int wc = 1; wc < 4; ++wc)
            t2_merge(v0, i0, v1, i1, e_v0[tid][wc], e_i0[tid][wc], e_v1[tid][wc], e_i1[tid][wc]);
        size_t o = (size_t)split * CAP + m0 + tid;
        rs_v0[o] = v0; rs_i0[o] = i0; rs_v1[o] = v1; rs_i1[o] = i1;
    }
}

// ---------------- Kernel M2: merge rescan splits; wave-cooperative fp64 verdict --
__global__ __launch_bounds__(256) void vq_merge2(
    const float* __restrict__ X, const float* __restrict__ CB,
    const int* __restrict__ list, const unsigned int* __restrict__ counter,
    const float* __restrict__ rs_v0, const int* __restrict__ rs_i0,
    const float* __restrict__ rs_v1, const int* __restrict__ rs_i1,
    int* __restrict__ out_idx)
{
    int cnt = min((int)*counter, CAP);
    int m = blockIdx.x * 256 + threadIdx.x;
    const int lane = threadIdx.x & 63;
    bool active = m < cnt;
    int q = 0;
    float v0 = 3e38f, v1 = 3e38f; int i0 = 0x7fffffff, i1 = 0x7fffffff;
    if (active) {
        q = list[m];
        #pragma unroll
        for (int s = 0; s < NSPLIT; ++s) {
            size_t o = (size_t)s * CAP + m;
            t2_merge(v0, i0, v1, i1, rs_v0[o], rs_i0[o], rs_v1[o], rs_i1[o]);
        }
    }
    int pick = i0;
    unsigned long long need = __ballot(active && (v1 - v0 < W2));
    while (need) {
        int src = __ffsll((long long)need) - 1;
        need &= need - 1;
        int qq = __shfl(q, src), a = __shfl(i0, src), b = __shfl(i1, src);
        const float* xr  = X  + (size_t)qq * DDIM + lane * 8;
        const float* c0p = CB + (size_t)a  * DDIM + lane * 8;
        const float* c1p = CB + (size_t)b  * DDIM + lane * 8;
        double d0 = 0.0, d1 = 0.0;
        #pragma unroll
        for (int j = 0; j < 8; ++j) {
            double xv = (double)xr[j];
            double e0 = xv - (double)c0p[j]; d0 = fma(e0, e0, d0);
            double e1 = xv - (double)c1p[j]; d1 = fma(e1, e1, d1);
        }
        #pragma unroll
        for (int off = 1; off < 64; off <<= 1) {
            d0 += __shfl_xor(d0, off);
            d1 += __shfl_xor(d1, off);
        }
        if (lane == src) {
            bool tb = (d1 < d0) || (d1 == d0 && b < a);
            pick = tb ? b : a;
        }
    }
    if (active) out_idx[q] = pick;
}

// ---------------- Kernel G: gather codebook rows (wave per query) ----------------
__global__ __launch_bounds__(256) void vq_gather(
    const float* __restrict__ CB, const int* __restrict__ out_idx,
    float* __restrict__ out)
{
    const int wave = (blockIdx.x * 256 + threadIdx.x) >> 6;   // 0..4095
    const int lane = threadIdx.x & 63;
    for (int q = wave; q < BT_N; q += 4096) {
        int idx = out_idx[q];
        const float4* src = (const float4*)(CB + (size_t)idx * DDIM);
        float4* dst = (float4*)(out + (size_t)q * DDIM);
        dst[lane]      = src[lane];
        dst[lane + 64] = src[lane + 64];
    }
}

// ---------------- launcher ----------------
extern "C" void kernel_launch(void* const* d_in, const int* in_sizes, int n_in,
                              void* d_out, int out_size, void* d_ws, size_t ws_size,
                              hipStream_t stream) {
    const float* X  = (const float*)d_in[0];   // [32768,512]
    const float* CB = (const float*)d_in[1];   // [4096,512]
    float* out = (float*)d_out;

    char* ws = (char*)d_ws;
    _Float16* Xh       = (_Float16*)(ws + OFF_XH);
    _Float16* Ch       = (_Float16*)(ws + OFF_CH);
    _Float16* Cl       = (_Float16*)(ws + OFF_CL);
    float*    cnormP   = (float*)(ws + OFF_CNP);
    double*   cnorm_dp = (double*)(ws + OFF_CND);
    float*    ws_v0    = (float*)(ws + OFF_V0);
    int*      ws_i0    = (int*)(ws + OFF_I0);
    float*    ws_v1    = (float*)(ws + OFF_V1);
    int*      out_idx  = (int*)(ws + OFF_OIDX);
    int*      list     = (int*)(ws + OFF_LIST);
    unsigned int* counter = (unsigned int*)(ws + OFF_CNT);
    float*    rs_v0    = (float*)(ws + OFF_RSV0);
    int*      rs_i0    = (int*)(ws + OFF_RSI0);
    float*    rs_v1    = (float*)(ws + OFF_RSV1);
    int*      rs_i1    = (int*)(ws + OFF_RSI1);

    hipMemsetAsync(counter, 0, 4, stream);
    vq_cvt_x<<<2048, 256, 0, stream>>>(X, Xh, BT_N * DDIM / 8);
    vq_cvt_cb<<<KCB / 4, 256, 0, stream>>>(CB, Ch, Cl, cnormP, cnorm_dp);
    vq_gemm<<<1024, 256, 0, stream>>>(Xh, Ch, cnormP, ws_v0, ws_i0, ws_v1);
    vq_merge<<<BT_N / 256, 256, 0, stream>>>(ws_v0, ws_i0, ws_v1, out_idx, list, counter);
    vq_rescan<<<dim3(CAP / 64, NSPLIT), 256, 0, stream>>>(X, Ch, Cl, cnormP, list, counter,
                                                          rs_v0, rs_i0, rs_v1, rs_i1);
    vq_merge2<<<CAP / 256, 256, 0, stream>>>(X, CB, list, counter,
                                             rs_v0, rs_i0, rs_v1, rs_i1, out_idx);
    vq_gather<<<1024, 256, 0, stream>>>(CB, out_idx, out);
}